// Round 1
// baseline (4962.757 us; speedup 1.0000x reference)
//
#include <hip/hip_runtime.h>

// Problem constants (from the reference file)
#define NN 100000      // nodes
#define EE 800000      // edges per type
#define TT 3           // edge types
#define D  128         // feature dim (in == out)

// out[n][d] = b0[d]+b1[d]+b2[d]  (bias sum; aggregation accumulates on top)
__global__ void init_out_kernel(const float* __restrict__ b, float* __restrict__ out) {
    int idx = blockIdx.x * blockDim.x + threadIdx.x;
    if (idx >= NN * D) return;
    int d = idx & (D - 1);
    out[idx] = b[d] + b[D + d] + b[2 * D + d];
}

// xw[n][d] = sum_k x[n][k] * W[k][d]   (one node per 128-thread block)
__global__ void xw_kernel(const float* __restrict__ x, const float* __restrict__ W,
                          float* __restrict__ xw) {
    int n = blockIdx.x;
    int d = threadIdx.x;
    __shared__ float xs[D];
    xs[d] = x[(size_t)n * D + d];
    __syncthreads();
    float acc = 0.f;
#pragma unroll 8
    for (int k = 0; k < D; ++k) acc += xs[k] * W[(size_t)k * D + d];
    xw[(size_t)n * D + d] = acc;
}

// deg[dst[e]] += 1
__global__ void deg_kernel(const int* __restrict__ dst, float* __restrict__ deg, int E) {
    int e = blockIdx.x * blockDim.x + threadIdx.x;
    if (e < E) atomicAdd(&deg[dst[e]], 1.0f);
}

// deg -> dis = rsqrt(deg + 1)   (+1 = self-loop; always > 0)
__global__ void dis_kernel(float* __restrict__ deg) {
    int n = blockIdx.x * blockDim.x + threadIdx.x;
    if (n < NN) deg[n] = rsqrtf(deg[n] + 1.0f);
}

// self-loop: out[n] += xw[n] * dis[n]^2   (unique (n,c) per thread -> plain RMW)
__global__ void selfloop_kernel(const float* __restrict__ xw, const float* __restrict__ dis,
                                float* __restrict__ out) {
    int idx = blockIdx.x * blockDim.x + threadIdx.x;  // NN*32 threads, float4 chunks
    if (idx >= NN * 32) return;
    int n = idx >> 5, c = idx & 31;
    float s = dis[n] * dis[n];
    float4 v = ((const float4*)(xw + (size_t)n * D))[c];
    float4* o = ((float4*)(out + (size_t)n * D)) + c;
    float4 ov = *o;
    ov.x += v.x * s; ov.y += v.y * s; ov.z += v.z * s; ov.w += v.w * s;
    *o = ov;
}

// edges: out[dst[e]] += xw[src[e]] * dis[src]*dis[dst]   (32 threads/edge, float4 each)
__global__ void scatter_kernel(const int* __restrict__ src, const int* __restrict__ dst,
                               const float* __restrict__ dis, const float* __restrict__ xw,
                               float* __restrict__ out, int E) {
    int tid = blockIdx.x * blockDim.x + threadIdx.x;
    int e = tid >> 5;
    if (e >= E) return;
    int c = tid & 31;
    int s = src[e], t = dst[e];
    float norm = dis[s] * dis[t];
    float4 v = ((const float4*)(xw + (size_t)s * D))[c];
    float* o = out + (size_t)t * D + c * 4;
    atomicAdd(o + 0, v.x * norm);
    atomicAdd(o + 1, v.y * norm);
    atomicAdd(o + 2, v.z * norm);
    atomicAdd(o + 3, v.w * norm);
}

extern "C" void kernel_launch(void* const* d_in, const int* in_sizes, int n_in,
                              void* d_out, int out_size, void* d_ws, size_t ws_size,
                              hipStream_t stream) {
    const float* x     = (const float*)d_in[0];   // [NN, D]
    const int*   edges = (const int*)d_in[1];     // [TT, 2, EE]
    const float* W     = (const float*)d_in[2];   // [TT, D, D]
    const float* b     = (const float*)d_in[3];   // [TT, D]
    float*       out   = (float*)d_out;           // [NN, D]

    float* xw  = (float*)d_ws;                    // NN*D floats (51.2 MB), reused per type
    float* deg = xw + (size_t)NN * D;             // NN floats (doubles as dis)

    // init out = sum of biases
    {
        int total = NN * D;
        init_out_kernel<<<(total + 255) / 256, 256, 0, stream>>>(b, out);
    }

    for (int t = 0; t < TT; ++t) {
        const int* src = edges + (size_t)t * 2 * EE;
        const int* dst = src + EE;
        const float* Wt = W + (size_t)t * D * D;

        // 1) xw = x @ W_t
        xw_kernel<<<NN, D, 0, stream>>>(x, Wt, xw);

        // 2) degree -> dis
        hipMemsetAsync(deg, 0, (size_t)NN * sizeof(float), stream);
        deg_kernel<<<(EE + 255) / 256, 256, 0, stream>>>(dst, deg, EE);
        dis_kernel<<<(NN + 255) / 256, 256, 0, stream>>>(deg);

        // 3) self-loop contribution
        {
            int total = NN * 32;
            selfloop_kernel<<<(total + 255) / 256, 256, 0, stream>>>(xw, deg, out);
        }

        // 4) edge scatter-aggregate
        {
            long long total = (long long)EE * 32;
            scatter_kernel<<<(int)((total + 255) / 256), 256, 0, stream>>>(src, dst, deg, xw, out, EE);
        }
    }
}

// Round 2
// 995.784 us; speedup vs baseline: 4.9838x; 4.9838x over previous
//
#include <hip/hip_runtime.h>

#define NN 100000      // nodes
#define EE 800000      // edges per type
#define TT 3           // edge types
#define D  128         // feature dim

typedef unsigned short bf16_t;

__device__ __forceinline__ bf16_t f2bf(float f) {
    unsigned u = __float_as_uint(f);
    u += 0x7fff + ((u >> 16) & 1);      // round-to-nearest-even
    return (bf16_t)(u >> 16);
}
__device__ __forceinline__ float bf2f(bf16_t h) {
    return __uint_as_float(((unsigned)h) << 16);
}

// ---------------- GEMM: xw[t] = x @ W_t (f32 acc, bf16 store) ----------------
// 16 nodes per 256-thread block; x rows staged in LDS; thread owns (node, 8-dim chunk)
__global__ void xw_kernel(const float* __restrict__ x, const float* __restrict__ W,
                          bf16_t* __restrict__ xw) {
    __shared__ float xs[16 * D];
    int tid = threadIdx.x;
    size_t n0 = (size_t)blockIdx.x * 16;
    const float4* xg = (const float4*)(x + n0 * D);
    float4* xs4 = (float4*)xs;
    xs4[tid] = xg[tid];
    xs4[tid + 256] = xg[tid + 256];
    __syncthreads();

    int n  = tid >> 4;          // 0..15
    int dg = (tid & 15) << 3;   // 0,8,...,120
    float acc[8];
#pragma unroll
    for (int i = 0; i < 8; ++i) acc[i] = 0.f;

#pragma unroll 4
    for (int k = 0; k < D; ++k) {
        float xv = xs[n * D + k];
        float4 w0 = *(const float4*)(W + (size_t)k * D + dg);
        float4 w1 = *(const float4*)(W + (size_t)k * D + dg + 4);
        acc[0] += xv * w0.x; acc[1] += xv * w0.y;
        acc[2] += xv * w0.z; acc[3] += xv * w0.w;
        acc[4] += xv * w1.x; acc[5] += xv * w1.y;
        acc[6] += xv * w1.z; acc[7] += xv * w1.w;
    }

    uint4 p;
    p.x = (unsigned)f2bf(acc[0]) | ((unsigned)f2bf(acc[1]) << 16);
    p.y = (unsigned)f2bf(acc[2]) | ((unsigned)f2bf(acc[3]) << 16);
    p.z = (unsigned)f2bf(acc[4]) | ((unsigned)f2bf(acc[5]) << 16);
    p.w = (unsigned)f2bf(acc[6]) | ((unsigned)f2bf(acc[7]) << 16);
    *(uint4*)(xw + (n0 + (size_t)n) * D + dg) = p;
}

// ---------------- degree count (int atomics), per type ----------------
__global__ void deg_all_kernel(const int* __restrict__ edges, int* __restrict__ deg3) {
    int e = blockIdx.x * 256 + threadIdx.x;
    int t = blockIdx.y;
    if (e < EE) {
        int dn = edges[(size_t)t * 2 * EE + EE + e];
        atomicAdd(&deg3[t * NN + dn], 1);
    }
}

// dis3[t][n] = rsqrt(deg+1); cnt[n] = total in-degree over types
__global__ void dis_cnt_kernel(const int* __restrict__ deg3, float* __restrict__ dis3,
                               int* __restrict__ cnt) {
    int n = blockIdx.x * 256 + threadIdx.x;
    if (n >= NN) return;
    int d0 = deg3[n], d1 = deg3[NN + n], d2 = deg3[2 * NN + n];
    cnt[n] = d0 + d1 + d2;
    dis3[n]          = rsqrtf((float)d0 + 1.f);
    dis3[NN + n]     = rsqrtf((float)d1 + 1.f);
    dis3[2 * NN + n] = rsqrtf((float)d2 + 1.f);
}

// ---------------- exclusive scan of cnt -> offs (3 kernels) ----------------
__global__ void scan1_kernel(const int* __restrict__ cnt, int* __restrict__ bsum) {
    __shared__ int s[256];
    int i = blockIdx.x * 256 + threadIdx.x;
    s[threadIdx.x] = (i < NN) ? cnt[i] : 0;
    __syncthreads();
    for (int off = 128; off > 0; off >>= 1) {
        if (threadIdx.x < off) s[threadIdx.x] += s[threadIdx.x + off];
        __syncthreads();
    }
    if (threadIdx.x == 0) bsum[blockIdx.x] = s[0];
}

__global__ void scan2_kernel(int* __restrict__ bsum, int nblk) {
    __shared__ int s[512];
    int tid = threadIdx.x;
    s[tid] = (tid < nblk) ? bsum[tid] : 0;
    __syncthreads();
    for (int off = 1; off < 512; off <<= 1) {
        int t = 0;
        if (tid >= off) t = s[tid - off];
        __syncthreads();
        if (tid >= off) s[tid] += t;
        __syncthreads();
    }
    if (tid < nblk) bsum[tid] = (tid == 0) ? 0 : s[tid - 1];  // exclusive
}

__global__ void scan3_kernel(const int* __restrict__ cnt, const int* __restrict__ bsum,
                             int* __restrict__ offs, int* __restrict__ cursor) {
    __shared__ int s[256];
    int i = blockIdx.x * 256 + threadIdx.x;
    int v = (i < NN) ? cnt[i] : 0;
    s[threadIdx.x] = v;
    __syncthreads();
    for (int off = 1; off < 256; off <<= 1) {
        int t = 0;
        if (threadIdx.x >= off) t = s[threadIdx.x - off];
        __syncthreads();
        if (threadIdx.x >= off) s[threadIdx.x] += t;
        __syncthreads();
    }
    if (i < NN) {
        int o = bsum[blockIdx.x] + s[threadIdx.x] - v;  // exclusive
        offs[i] = o;
        cursor[i] = o;
    }
}

// ---------------- CSR fill: recs sorted by dst ----------------
// rec = (t*NN + src, norm)
__global__ void fill_kernel(const int* __restrict__ edges, const float* __restrict__ dis3,
                            int* __restrict__ cursor, int2* __restrict__ recs) {
    int e = blockIdx.x * 256 + threadIdx.x;
    int t = blockIdx.y;
    if (e >= EE) return;
    const int* base = edges + (size_t)t * 2 * EE;
    int sn = base[e];
    int dn = base[EE + e];
    float norm = dis3[t * NN + sn] * dis3[t * NN + dn];
    int pos = atomicAdd(&cursor[dn], 1);
    recs[pos] = make_int2(t * NN + sn, __float_as_int(norm));
}

// ---------------- gather: one block (128 thr) per node, plain stores ----------------
__global__ void gather_kernel(const bf16_t* __restrict__ xw3, const float* __restrict__ dis3,
                              const int* __restrict__ offs, const int* __restrict__ cnt,
                              const int2* __restrict__ recs, const float* __restrict__ b,
                              float* __restrict__ out) {
    int n = blockIdx.x;
    int d = threadIdx.x;

    float acc = b[d] + b[D + d] + b[2 * D + d];

    // self-loops: xw_t[n] * dis_t[n]^2
#pragma unroll
    for (int t = 0; t < TT; ++t) {
        float dv = dis3[t * NN + n];
        acc += bf2f(xw3[((size_t)(t * NN + n)) * D + d]) * dv * dv;
    }

    int s0 = offs[n];
    int c  = cnt[n];
    int j = 0;
    for (; j + 4 <= c; j += 4) {
        int2 r0 = recs[s0 + j];
        int2 r1 = recs[s0 + j + 1];
        int2 r2 = recs[s0 + j + 2];
        int2 r3 = recs[s0 + j + 3];
        float v0 = bf2f(xw3[(size_t)r0.x * D + d]);
        float v1 = bf2f(xw3[(size_t)r1.x * D + d]);
        float v2 = bf2f(xw3[(size_t)r2.x * D + d]);
        float v3 = bf2f(xw3[(size_t)r3.x * D + d]);
        acc += v0 * __int_as_float(r0.y) + v1 * __int_as_float(r1.y)
             + v2 * __int_as_float(r2.y) + v3 * __int_as_float(r3.y);
    }
    for (; j < c; ++j) {
        int2 r = recs[s0 + j];
        acc += bf2f(xw3[(size_t)r.x * D + d]) * __int_as_float(r.y);
    }

    out[(size_t)n * D + d] = acc;
}

extern "C" void kernel_launch(void* const* d_in, const int* in_sizes, int n_in,
                              void* d_out, int out_size, void* d_ws, size_t ws_size,
                              hipStream_t stream) {
    const float* x     = (const float*)d_in[0];   // [NN, D]
    const int*   edges = (const int*)d_in[1];     // [TT, 2, EE]
    const float* W     = (const float*)d_in[2];   // [TT, D, D]
    const float* b     = (const float*)d_in[3];   // [TT, D]
    float*       out   = (float*)d_out;           // [NN, D]

    // workspace layout (all offsets 16B-aligned)
    char* w = (char*)d_ws;
    bf16_t* xw3  = (bf16_t*)w;                               // 3*NN*D bf16 = 76.8 MB
    float*  dis3 = (float*)(w + (size_t)3 * NN * D * 2);     // 3*NN f32
    int*    deg3 = (int*)((char*)dis3 + (size_t)3 * NN * 4); // 3*NN int
    int*    cnt    = deg3 + 3 * NN;                          // NN
    int*    offs   = cnt + NN;                               // NN
    int*    cursor = offs + NN;                              // NN
    int*    bsum   = cursor + NN;                            // 512
    int2*   recs   = (int2*)(bsum + 512);                    // 3*EE int2 = 19.2 MB

    const int nblk = (NN + 255) / 256;  // 391

    hipMemsetAsync(deg3, 0, (size_t)3 * NN * sizeof(int), stream);

    // 1) per-type GEMM into bf16
    for (int t = 0; t < TT; ++t) {
        xw_kernel<<<NN / 16, 256, 0, stream>>>(x, W + (size_t)t * D * D,
                                               xw3 + (size_t)t * NN * D);
    }

    // 2) degrees + dis + per-node total count
    {
        dim3 g((EE + 255) / 256, TT);
        deg_all_kernel<<<g, 256, 0, stream>>>(edges, deg3);
    }
    dis_cnt_kernel<<<nblk, 256, 0, stream>>>(deg3, dis3, cnt);

    // 3) exclusive scan cnt -> offs, cursor
    scan1_kernel<<<nblk, 256, 0, stream>>>(cnt, bsum);
    scan2_kernel<<<1, 512, 0, stream>>>(bsum, nblk);
    scan3_kernel<<<nblk, 256, 0, stream>>>(cnt, bsum, offs, cursor);

    // 4) fill CSR records sorted by dst
    {
        dim3 g((EE + 255) / 256, TT);
        fill_kernel<<<g, 256, 0, stream>>>(edges, dis3, cursor, recs);
    }

    // 5) gather-aggregate, one plain store per output element
    gather_kernel<<<NN, D, 0, stream>>>(xw3, dis3, offs, cnt, recs, b, out);
}

// Round 3
// 534.091 us; speedup vs baseline: 9.2920x; 1.8644x over previous
//
#include <hip/hip_runtime.h>

#define NN 100000      // nodes
#define EE 800000      // edges per type
#define TT 3           // edge types
#define D  128         // feature dim

typedef unsigned short bf16_t;

typedef __bf16 bf16x8_t __attribute__((ext_vector_type(8)));
typedef float  f32x4_t  __attribute__((ext_vector_type(4)));

union ABFrag { bf16x8_t v; ushort u[8]; uint4 q; };

__device__ __forceinline__ bf16_t f2bf(float f) {
    unsigned u = __float_as_uint(f);
    u += 0x7fff + ((u >> 16) & 1);      // round-to-nearest-even
    return (bf16_t)(u >> 16);
}
__device__ __forceinline__ float bf2f(bf16_t h) {
    return __uint_as_float(((unsigned)h) << 16);
}

// ---------------- W transpose + bf16 convert: WT[t][n][k] = bf16(W[t][k][n]) ----------------
__global__ void wconv_kernel(const float* __restrict__ W, bf16_t* __restrict__ WT) {
    int t = blockIdx.y, n = blockIdx.x, k = threadIdx.x;
    WT[((size_t)t * D + n) * D + k] = f2bf(W[((size_t)t * D + k) * D + n]);
}

// ---------------- MFMA GEMM: xw3[t] = x @ W_t for all 3 types ----------------
// Block = 256 thr = 4 waves; wave owns 16 rows; A-frags reused across 3 types x 8 N-blocks.
__global__ __launch_bounds__(256) void xw_mfma_kernel(const float* __restrict__ x,
                                                      const bf16_t* __restrict__ WT,
                                                      bf16_t* __restrict__ xw3) {
    int lane = threadIdx.x & 63;
    int wave = threadIdx.x >> 6;
    int quad = lane >> 4;
    int lid  = lane & 15;

    int row  = blockIdx.x * 64 + wave * 16 + lid;
    int rowc = row < NN ? row : NN - 1;           // clamp for load; store is guarded

    // A fragments: 4 K-slices of 32, lane holds A[m=lid][k=slice*32+quad*8+j]
    ABFrag a[4];
    const float* xr = x + (size_t)rowc * D;
#pragma unroll
    for (int s = 0; s < 4; ++s) {
        int k0 = s * 32 + quad * 8;
        float4 f0 = *(const float4*)(xr + k0);
        float4 f1 = *(const float4*)(xr + k0 + 4);
        a[s].u[0] = f2bf(f0.x); a[s].u[1] = f2bf(f0.y);
        a[s].u[2] = f2bf(f0.z); a[s].u[3] = f2bf(f0.w);
        a[s].u[4] = f2bf(f1.x); a[s].u[5] = f2bf(f1.y);
        a[s].u[6] = f2bf(f1.z); a[s].u[7] = f2bf(f1.w);
    }

    int outrow0 = blockIdx.x * 64 + wave * 16 + quad * 4;   // C/D: row = quad*4 + reg

#pragma unroll
    for (int t = 0; t < TT; ++t) {
        const bf16_t* wt = WT + (size_t)t * D * D;
#pragma unroll
        for (int nb = 0; nb < 8; ++nb) {
            const bf16_t* wn = wt + (size_t)(nb * 16 + lid) * D;  // B[n=lid][k]
            f32x4_t acc = {0.f, 0.f, 0.f, 0.f};
#pragma unroll
            for (int s = 0; s < 4; ++s) {
                ABFrag bfr;
                bfr.q = *(const uint4*)(wn + s * 32 + quad * 8);
                acc = __builtin_amdgcn_mfma_f32_16x16x32_bf16(a[s].v, bfr.v, acc, 0, 0, 0);
            }
#pragma unroll
            for (int r = 0; r < 4; ++r) {
                int orow = outrow0 + r;
                if (orow < NN)
                    xw3[((size_t)t * NN + orow) * D + nb * 16 + lid] = f2bf(acc[r]);
            }
        }
    }
}

// ---------------- degree count (int atomics), per type ----------------
__global__ void deg_all_kernel(const int* __restrict__ edges, int* __restrict__ deg3) {
    int e = blockIdx.x * 256 + threadIdx.x;
    int t = blockIdx.y;
    if (e < EE) {
        int dn = edges[(size_t)t * 2 * EE + EE + e];
        atomicAdd(&deg3[t * NN + dn], 1);
    }
}

// dis3[t][n] = rsqrt(deg+1); cnt[n] = total in-degree over types
__global__ void dis_cnt_kernel(const int* __restrict__ deg3, float* __restrict__ dis3,
                               int* __restrict__ cnt) {
    int n = blockIdx.x * 256 + threadIdx.x;
    if (n >= NN) return;
    int d0 = deg3[n], d1 = deg3[NN + n], d2 = deg3[2 * NN + n];
    cnt[n] = d0 + d1 + d2;
    dis3[n]          = rsqrtf((float)d0 + 1.f);
    dis3[NN + n]     = rsqrtf((float)d1 + 1.f);
    dis3[2 * NN + n] = rsqrtf((float)d2 + 1.f);
}

// ---------------- exclusive scan of cnt -> offs ----------------
__global__ void scan1_kernel(const int* __restrict__ cnt, int* __restrict__ bsum) {
    __shared__ int s[256];
    int i = blockIdx.x * 256 + threadIdx.x;
    s[threadIdx.x] = (i < NN) ? cnt[i] : 0;
    __syncthreads();
    for (int off = 128; off > 0; off >>= 1) {
        if (threadIdx.x < off) s[threadIdx.x] += s[threadIdx.x + off];
        __syncthreads();
    }
    if (threadIdx.x == 0) bsum[blockIdx.x] = s[0];
}

__global__ void scan2_kernel(int* __restrict__ bsum, int nblk) {
    __shared__ int s[512];
    int tid = threadIdx.x;
    s[tid] = (tid < nblk) ? bsum[tid] : 0;
    __syncthreads();
    for (int off = 1; off < 512; off <<= 1) {
        int t = 0;
        if (tid >= off) t = s[tid - off];
        __syncthreads();
        if (tid >= off) s[tid] += t;
        __syncthreads();
    }
    if (tid < nblk) bsum[tid] = (tid == 0) ? 0 : s[tid - 1];  // exclusive
}

__global__ void scan3_kernel(const int* __restrict__ cnt, const int* __restrict__ bsum,
                             int* __restrict__ offs, int* __restrict__ cursor) {
    __shared__ int s[256];
    int i = blockIdx.x * 256 + threadIdx.x;
    int v = (i < NN) ? cnt[i] : 0;
    s[threadIdx.x] = v;
    __syncthreads();
    for (int off = 1; off < 256; off <<= 1) {
        int t = 0;
        if (threadIdx.x >= off) t = s[threadIdx.x - off];
        __syncthreads();
        if (threadIdx.x >= off) s[threadIdx.x] += t;
        __syncthreads();
    }
    if (i < NN) {
        int o = bsum[blockIdx.x] + s[threadIdx.x] - v;  // exclusive
        offs[i] = o;
        cursor[i] = o;
    }
}

// ---------------- CSR fill: recs sorted by dst; rec = (t*NN+src, norm) ----------------
__global__ void fill_kernel(const int* __restrict__ edges, const float* __restrict__ dis3,
                            int* __restrict__ cursor, int2* __restrict__ recs) {
    int e = blockIdx.x * 256 + threadIdx.x;
    int t = blockIdx.y;
    if (e >= EE) return;
    const int* base = edges + (size_t)t * 2 * EE;
    int sn = base[e];
    int dn = base[EE + e];
    float norm = dis3[t * NN + sn] * dis3[t * NN + dn];
    int pos = atomicAdd(&cursor[dn], 1);
    recs[pos] = make_int2(t * NN + sn, __float_as_int(norm));
}

// ---------------- gather: one block (128 thr) per node, plain stores ----------------
__global__ void gather_kernel(const bf16_t* __restrict__ xw3, const float* __restrict__ dis3,
                              const int* __restrict__ offs, const int* __restrict__ cnt,
                              const int2* __restrict__ recs, const float* __restrict__ b,
                              float* __restrict__ out) {
    int n = blockIdx.x;
    int d = threadIdx.x;

    float acc = b[d] + b[D + d] + b[2 * D + d];

#pragma unroll
    for (int t = 0; t < TT; ++t) {
        float dv = dis3[t * NN + n];
        acc += bf2f(xw3[((size_t)(t * NN + n)) * D + d]) * dv * dv;
    }

    int s0 = offs[n];
    int c  = cnt[n];
    int j = 0;
    for (; j + 4 <= c; j += 4) {
        int2 r0 = recs[s0 + j];
        int2 r1 = recs[s0 + j + 1];
        int2 r2 = recs[s0 + j + 2];
        int2 r3 = recs[s0 + j + 3];
        float v0 = bf2f(xw3[(size_t)r0.x * D + d]);
        float v1 = bf2f(xw3[(size_t)r1.x * D + d]);
        float v2 = bf2f(xw3[(size_t)r2.x * D + d]);
        float v3 = bf2f(xw3[(size_t)r3.x * D + d]);
        acc += v0 * __int_as_float(r0.y) + v1 * __int_as_float(r1.y)
             + v2 * __int_as_float(r2.y) + v3 * __int_as_float(r3.y);
    }
    for (; j < c; ++j) {
        int2 r = recs[s0 + j];
        acc += bf2f(xw3[(size_t)r.x * D + d]) * __int_as_float(r.y);
    }

    out[(size_t)n * D + d] = acc;
}

extern "C" void kernel_launch(void* const* d_in, const int* in_sizes, int n_in,
                              void* d_out, int out_size, void* d_ws, size_t ws_size,
                              hipStream_t stream) {
    const float* x     = (const float*)d_in[0];   // [NN, D]
    const int*   edges = (const int*)d_in[1];     // [TT, 2, EE]
    const float* W     = (const float*)d_in[2];   // [TT, D, D]
    const float* b     = (const float*)d_in[3];   // [TT, D]
    float*       out   = (float*)d_out;           // [NN, D]

    // workspace layout
    char* w = (char*)d_ws;
    bf16_t* xw3  = (bf16_t*)w;                               // 3*NN*D bf16 = 76.8 MB
    float*  dis3 = (float*)(w + (size_t)3 * NN * D * 2);     // 3*NN f32
    int*    deg3 = (int*)((char*)dis3 + (size_t)3 * NN * 4); // 3*NN int
    int*    cnt    = deg3 + 3 * NN;                          // NN
    int*    offs   = cnt + NN;                               // NN
    int*    cursor = offs + NN;                              // NN
    int*    bsum   = cursor + NN;                            // 512
    int2*   recs   = (int2*)(bsum + 512);                    // 3*EE int2 = 19.2 MB
    bf16_t* WT     = (bf16_t*)(recs + (size_t)3 * EE);       // 3*D*D bf16 = 96 KB

    const int nblk = (NN + 255) / 256;  // 391

    hipMemsetAsync(deg3, 0, (size_t)3 * NN * sizeof(int), stream);

    // 0) W -> bf16 transposed
    {
        dim3 g(D, TT);
        wconv_kernel<<<g, D, 0, stream>>>(W, WT);
    }

    // 1) fused MFMA GEMM for all 3 types
    xw_mfma_kernel<<<(NN + 63) / 64, 256, 0, stream>>>(x, WT, xw3);

    // 2) degrees + dis + per-node total count
    {
        dim3 g((EE + 255) / 256, TT);
        deg_all_kernel<<<g, 256, 0, stream>>>(edges, deg3);
    }
    dis_cnt_kernel<<<nblk, 256, 0, stream>>>(deg3, dis3, cnt);

    // 3) exclusive scan cnt -> offs, cursor
    scan1_kernel<<<nblk, 256, 0, stream>>>(cnt, bsum);
    scan2_kernel<<<1, 512, 0, stream>>>(bsum, nblk);
    scan3_kernel<<<nblk, 256, 0, stream>>>(cnt, bsum, offs, cursor);

    // 4) fill CSR records sorted by dst
    {
        dim3 g((EE + 255) / 256, TT);
        fill_kernel<<<g, 256, 0, stream>>>(edges, dis3, cursor, recs);
    }

    // 5) gather-aggregate, one plain store per output element
    gather_kernel<<<NN, D, 0, stream>>>(xw3, dis3, offs, cnt, recs, b, out);
}

// Round 4
// 519.806 us; speedup vs baseline: 9.5473x; 1.0275x over previous
//
#include <hip/hip_runtime.h>

#define NN 100000      // nodes
#define EE 800000      // edges per type
#define TT 3           // edge types
#define D  128         // feature dim

typedef unsigned short bf16_t;

typedef __bf16 bf16x8_t __attribute__((ext_vector_type(8)));
typedef float  f32x4_t  __attribute__((ext_vector_type(4)));

union ABFrag { bf16x8_t v; ushort u[8]; uint4 q; };

__device__ __forceinline__ bf16_t f2bf(float f) {
    unsigned u = __float_as_uint(f);
    u += 0x7fff + ((u >> 16) & 1);      // round-to-nearest-even
    return (bf16_t)(u >> 16);
}
__device__ __forceinline__ float bf2f(bf16_t h) {
    return __uint_as_float(((unsigned)h) << 16);
}

// ---------------- W transpose + bf16 convert: WT[t][n][k] = bf16(W[t][k][n]) ----------------
__global__ void wconv_kernel(const float* __restrict__ W, bf16_t* __restrict__ WT) {
    int t = blockIdx.y, n = blockIdx.x, k = threadIdx.x;
    WT[((size_t)t * D + n) * D + k] = f2bf(W[((size_t)t * D + k) * D + n]);
}

// ---------------- MFMA GEMM: xw3[t] = x @ W_t for all 3 types ----------------
__global__ __launch_bounds__(256) void xw_mfma_kernel(const float* __restrict__ x,
                                                      const bf16_t* __restrict__ WT,
                                                      bf16_t* __restrict__ xw3) {
    int lane = threadIdx.x & 63;
    int wave = threadIdx.x >> 6;
    int quad = lane >> 4;
    int lid  = lane & 15;

    int row  = blockIdx.x * 64 + wave * 16 + lid;
    int rowc = row < NN ? row : NN - 1;           // clamp for load; store is guarded

    ABFrag a[4];
    const float* xr = x + (size_t)rowc * D;
#pragma unroll
    for (int s = 0; s < 4; ++s) {
        int k0 = s * 32 + quad * 8;
        float4 f0 = *(const float4*)(xr + k0);
        float4 f1 = *(const float4*)(xr + k0 + 4);
        a[s].u[0] = f2bf(f0.x); a[s].u[1] = f2bf(f0.y);
        a[s].u[2] = f2bf(f0.z); a[s].u[3] = f2bf(f0.w);
        a[s].u[4] = f2bf(f1.x); a[s].u[5] = f2bf(f1.y);
        a[s].u[6] = f2bf(f1.z); a[s].u[7] = f2bf(f1.w);
    }

    int outrow0 = blockIdx.x * 64 + wave * 16 + quad * 4;   // C/D: row = quad*4 + reg

#pragma unroll
    for (int t = 0; t < TT; ++t) {
        const bf16_t* wt = WT + (size_t)t * D * D;
#pragma unroll
        for (int nb = 0; nb < 8; ++nb) {
            const bf16_t* wn = wt + (size_t)(nb * 16 + lid) * D;  // B[n=lid][k]
            f32x4_t acc = {0.f, 0.f, 0.f, 0.f};
#pragma unroll
            for (int s = 0; s < 4; ++s) {
                ABFrag bfr;
                bfr.q = *(const uint4*)(wn + s * 32 + quad * 8);
                acc = __builtin_amdgcn_mfma_f32_16x16x32_bf16(a[s].v, bfr.v, acc, 0, 0, 0);
            }
#pragma unroll
            for (int r = 0; r < 4; ++r) {
                int orow = outrow0 + r;
                if (orow < NN)
                    xw3[((size_t)t * NN + orow) * D + nb * 16 + lid] = f2bf(acc[r]);
            }
        }
    }
}

// ---------------- degree + rank (atomic returns within-segment rank), MLP=4 ----------------
__global__ void deg_rank_kernel(const int* __restrict__ edges, int* __restrict__ deg3,
                                int* __restrict__ rank) {
    int t = blockIdx.y;
    int e0 = (blockIdx.x * 256 + threadIdx.x) * 4;
    if (e0 >= EE) return;                         // EE % 4 == 0
    const int* dstp = edges + (size_t)t * 2 * EE + EE;
    int4 dn = *(const int4*)(dstp + e0);
    int* dg = deg3 + t * NN;
    int4 r;
    r.x = atomicAdd(&dg[dn.x], 1);
    r.y = atomicAdd(&dg[dn.y], 1);
    r.z = atomicAdd(&dg[dn.z], 1);
    r.w = atomicAdd(&dg[dn.w], 1);
    *(int4*)(rank + (size_t)t * EE + e0) = r;
}

// dis3[t][n] = rsqrt(deg+1); cnt[n] = total in-degree over types
__global__ void dis_cnt_kernel(const int* __restrict__ deg3, float* __restrict__ dis3,
                               int* __restrict__ cnt) {
    int n = blockIdx.x * 256 + threadIdx.x;
    if (n >= NN) return;
    int d0 = deg3[n], d1 = deg3[NN + n], d2 = deg3[2 * NN + n];
    cnt[n] = d0 + d1 + d2;
    dis3[n]          = rsqrtf((float)d0 + 1.f);
    dis3[NN + n]     = rsqrtf((float)d1 + 1.f);
    dis3[2 * NN + n] = rsqrtf((float)d2 + 1.f);
}

// ---------------- exclusive scan of cnt -> offs, offs3 ----------------
__global__ void scan1_kernel(const int* __restrict__ cnt, int* __restrict__ bsum) {
    __shared__ int s[256];
    int i = blockIdx.x * 256 + threadIdx.x;
    s[threadIdx.x] = (i < NN) ? cnt[i] : 0;
    __syncthreads();
    for (int off = 128; off > 0; off >>= 1) {
        if (threadIdx.x < off) s[threadIdx.x] += s[threadIdx.x + off];
        __syncthreads();
    }
    if (threadIdx.x == 0) bsum[blockIdx.x] = s[0];
}

__global__ void scan2_kernel(int* __restrict__ bsum, int nblk) {
    __shared__ int s[512];
    int tid = threadIdx.x;
    s[tid] = (tid < nblk) ? bsum[tid] : 0;
    __syncthreads();
    for (int off = 1; off < 512; off <<= 1) {
        int t = 0;
        if (tid >= off) t = s[tid - off];
        __syncthreads();
        if (tid >= off) s[tid] += t;
        __syncthreads();
    }
    if (tid < nblk) bsum[tid] = (tid == 0) ? 0 : s[tid - 1];  // exclusive
}

__global__ void scan3_kernel(const int* __restrict__ cnt, const int* __restrict__ bsum,
                             const int* __restrict__ deg3,
                             int* __restrict__ offs, int* __restrict__ offs3) {
    __shared__ int s[256];
    int i = blockIdx.x * 256 + threadIdx.x;
    int v = (i < NN) ? cnt[i] : 0;
    s[threadIdx.x] = v;
    __syncthreads();
    for (int off = 1; off < 256; off <<= 1) {
        int t = 0;
        if (threadIdx.x >= off) t = s[threadIdx.x - off];
        __syncthreads();
        if (threadIdx.x >= off) s[threadIdx.x] += t;
        __syncthreads();
    }
    if (i < NN) {
        int o = bsum[blockIdx.x] + s[threadIdx.x] - v;  // exclusive
        offs[i] = o;
        int d0 = deg3[i], d1 = deg3[NN + i];
        offs3[i]          = o;
        offs3[NN + i]     = o + d0;
        offs3[2 * NN + i] = o + d0 + d1;
    }
}

// ---------------- CSR fill: no atomics, 4B records, MLP=4 ----------------
// rec = (t << 17) | src
__global__ void fill_kernel(const int* __restrict__ edges, const int* __restrict__ rank,
                            const int* __restrict__ offs3, unsigned* __restrict__ recs) {
    int t = blockIdx.y;
    int e0 = (blockIdx.x * 256 + threadIdx.x) * 4;
    if (e0 >= EE) return;
    const int* base = edges + (size_t)t * 2 * EE;
    int4 sn = *(const int4*)(base + e0);
    int4 dn = *(const int4*)(base + EE + e0);
    int4 rk = *(const int4*)(rank + (size_t)t * EE + e0);
    const int* o3 = offs3 + t * NN;
    unsigned tb = (unsigned)t << 17;
    int p0 = o3[dn.x] + rk.x;
    int p1 = o3[dn.y] + rk.y;
    int p2 = o3[dn.z] + rk.z;
    int p3 = o3[dn.w] + rk.w;
    recs[p0] = tb | (unsigned)sn.x;
    recs[p1] = tb | (unsigned)sn.y;
    recs[p2] = tb | (unsigned)sn.z;
    recs[p3] = tb | (unsigned)sn.w;
}

// ---------------- gather: one block (128 thr) per node, plain stores ----------------
__global__ void gather_kernel(const bf16_t* __restrict__ xw3, const float* __restrict__ dis3,
                              const int* __restrict__ offs, const int* __restrict__ cnt,
                              const unsigned* __restrict__ recs, const float* __restrict__ b,
                              float* __restrict__ out) {
    int n = blockIdx.x;
    int d = threadIdx.x;

    float dn0 = dis3[n], dn1 = dis3[NN + n], dn2 = dis3[2 * NN + n];

    float acc = b[d] + b[D + d] + b[2 * D + d];
    acc += bf2f(xw3[(size_t)n * D + d]) * dn0 * dn0;
    acc += bf2f(xw3[(size_t)(NN + n) * D + d]) * dn1 * dn1;
    acc += bf2f(xw3[(size_t)(2 * NN + n) * D + d]) * dn2 * dn2;

    int s0 = offs[n];
    int c  = cnt[n];
    int j = 0;
    for (; j + 4 <= c; j += 4) {
        unsigned r0 = recs[s0 + j];
        unsigned r1 = recs[s0 + j + 1];
        unsigned r2 = recs[s0 + j + 2];
        unsigned r3 = recs[s0 + j + 3];
        int t0 = r0 >> 17, t1 = r1 >> 17, t2 = r2 >> 17, t3 = r3 >> 17;
        int i0 = t0 * NN + (int)(r0 & 0x1FFFF);
        int i1 = t1 * NN + (int)(r1 & 0x1FFFF);
        int i2 = t2 * NN + (int)(r2 & 0x1FFFF);
        int i3 = t3 * NN + (int)(r3 & 0x1FFFF);
        float v0 = bf2f(xw3[(size_t)i0 * D + d]);
        float v1 = bf2f(xw3[(size_t)i1 * D + d]);
        float v2 = bf2f(xw3[(size_t)i2 * D + d]);
        float v3 = bf2f(xw3[(size_t)i3 * D + d]);
        float nm0 = dis3[i0] * (t0 == 0 ? dn0 : (t0 == 1 ? dn1 : dn2));
        float nm1 = dis3[i1] * (t1 == 0 ? dn0 : (t1 == 1 ? dn1 : dn2));
        float nm2 = dis3[i2] * (t2 == 0 ? dn0 : (t2 == 1 ? dn1 : dn2));
        float nm3 = dis3[i3] * (t3 == 0 ? dn0 : (t3 == 1 ? dn1 : dn2));
        acc += v0 * nm0 + v1 * nm1 + v2 * nm2 + v3 * nm3;
    }
    for (; j < c; ++j) {
        unsigned r = recs[s0 + j];
        int t = r >> 17;
        int i = t * NN + (int)(r & 0x1FFFF);
        acc += bf2f(xw3[(size_t)i * D + d]) * dis3[i] * (t == 0 ? dn0 : (t == 1 ? dn1 : dn2));
    }

    out[(size_t)n * D + d] = acc;
}

extern "C" void kernel_launch(void* const* d_in, const int* in_sizes, int n_in,
                              void* d_out, int out_size, void* d_ws, size_t ws_size,
                              hipStream_t stream) {
    const float* x     = (const float*)d_in[0];   // [NN, D]
    const int*   edges = (const int*)d_in[1];     // [TT, 2, EE]
    const float* W     = (const float*)d_in[2];   // [TT, D, D]
    const float* b     = (const float*)d_in[3];   // [TT, D]
    float*       out   = (float*)d_out;           // [NN, D]

    // workspace layout (16B-aligned chunks)
    char* w = (char*)d_ws;
    bf16_t*   xw3   = (bf16_t*)w;                                  // 3*NN*D bf16 = 76.8 MB
    float*    dis3  = (float*)(w + (size_t)3 * NN * D * 2);        // 3*NN f32
    int*      deg3  = (int*)((char*)dis3 + (size_t)3 * NN * 4);    // 3*NN int
    int*      cnt   = deg3 + 3 * NN;                               // NN
    int*      offs  = cnt + NN;                                    // NN
    int*      offs3 = offs + NN;                                   // 3*NN
    int*      bsum  = offs3 + 3 * NN;                              // 512
    int*      rank  = bsum + 512;                                  // 3*EE = 9.6 MB
    unsigned* recs  = (unsigned*)(rank + (size_t)3 * EE);          // 3*EE = 9.6 MB
    bf16_t*   WT    = (bf16_t*)(recs + (size_t)3 * EE);            // 3*D*D bf16 = 96 KB

    const int nblk = (NN + 255) / 256;  // 391

    hipMemsetAsync(deg3, 0, (size_t)3 * NN * sizeof(int), stream);

    // 0) W -> bf16 transposed
    {
        dim3 g(D, TT);
        wconv_kernel<<<g, D, 0, stream>>>(W, WT);
    }

    // 1) fused MFMA GEMM for all 3 types
    xw_mfma_kernel<<<(NN + 63) / 64, 256, 0, stream>>>(x, WT, xw3);

    // 2) degree + rank (atomic return value = within-segment rank)
    {
        dim3 g((EE / 4 + 255) / 256, TT);
        deg_rank_kernel<<<g, 256, 0, stream>>>(edges, deg3, rank);
    }
    dis_cnt_kernel<<<nblk, 256, 0, stream>>>(deg3, dis3, cnt);

    // 3) exclusive scan cnt -> offs, per-type offs3
    scan1_kernel<<<nblk, 256, 0, stream>>>(cnt, bsum);
    scan2_kernel<<<1, 512, 0, stream>>>(bsum, nblk);
    scan3_kernel<<<nblk, 256, 0, stream>>>(cnt, bsum, deg3, offs, offs3);

    // 4) fill CSR records (no atomics, fire-and-forget 4B stores)
    {
        dim3 g((EE / 4 + 255) / 256, TT);
        fill_kernel<<<g, 256, 0, stream>>>(edges, rank, offs3, recs);
    }

    // 5) gather-aggregate, one plain store per output element
    gather_kernel<<<NN, D, 0, stream>>>(xw3, dis3, offs, cnt, recs, b, out);
}

// Round 5
// 490.936 us; speedup vs baseline: 10.1088x; 1.0588x over previous
//
#include <hip/hip_runtime.h>

#define NN 100000      // nodes
#define EE 800000      // edges per type
#define TT 3           // edge types
#define D  128         // feature dim
#define LSTRIDE 392    // 3*D + 8 pad (elements) -> 2-way LDS conflicts only (free)

typedef unsigned short bf16_t;

typedef __bf16 bf16x8_t __attribute__((ext_vector_type(8)));
typedef float  f32x4_t  __attribute__((ext_vector_type(4)));

union ABFrag { bf16x8_t v; ushort u[8]; uint4 q; };

__device__ __forceinline__ bf16_t f2bf(float f) {
    unsigned u = __float_as_uint(f);
    u += 0x7fff + ((u >> 16) & 1);      // round-to-nearest-even
    return (bf16_t)(u >> 16);
}
__device__ __forceinline__ float bf_lo(unsigned p) { return __uint_as_float(p << 16); }
__device__ __forceinline__ float bf_hi(unsigned p) { return __uint_as_float(p & 0xFFFF0000u); }

// ---------------- quantize x -> bf16 copy (25.6 MB, L3-resident gather target) -------------
__global__ void quant_kernel(const float* __restrict__ x, bf16_t* __restrict__ xq) {
    int i = (blockIdx.x * 256 + threadIdx.x) * 4;
    if (i >= NN * D) return;
    float4 f = *(const float4*)(x + i);
    uint2 p;
    p.x = (unsigned)f2bf(f.x) | ((unsigned)f2bf(f.y) << 16);
    p.y = (unsigned)f2bf(f.z) | ((unsigned)f2bf(f.w) << 16);
    *(uint2*)(xq + i) = p;
}

// ---------------- W transpose + bf16: WT[t][n][k] = bf16(W[t][k][n]) ----------------
__global__ void wconv_kernel(const float* __restrict__ W, bf16_t* __restrict__ WT) {
    int t = blockIdx.y, n = blockIdx.x, k = threadIdx.x;
    WT[((size_t)t * D + n) * D + k] = f2bf(W[((size_t)t * D + k) * D + n]);
}

// ---------------- degree + rank (atomic return = within-segment rank), MLP=4 ----------------
__global__ void deg_rank_kernel(const int* __restrict__ edges, int* __restrict__ deg3,
                                int* __restrict__ rank) {
    int t = blockIdx.y;
    int e0 = (blockIdx.x * 256 + threadIdx.x) * 4;
    if (e0 >= EE) return;                         // EE % 4 == 0
    const int* dstp = edges + (size_t)t * 2 * EE + EE;
    int4 dn = *(const int4*)(dstp + e0);
    int* dg = deg3 + t * NN;
    int4 r;
    r.x = atomicAdd(&dg[dn.x], 1);
    r.y = atomicAdd(&dg[dn.y], 1);
    r.z = atomicAdd(&dg[dn.z], 1);
    r.w = atomicAdd(&dg[dn.w], 1);
    *(int4*)(rank + (size_t)t * EE + e0) = r;
}

// dis3[t][n] = rsqrt(deg+1); cnt[n] = total in-degree over types
__global__ void dis_cnt_kernel(const int* __restrict__ deg3, float* __restrict__ dis3,
                               int* __restrict__ cnt) {
    int n = blockIdx.x * 256 + threadIdx.x;
    if (n >= NN) return;
    int d0 = deg3[n], d1 = deg3[NN + n], d2 = deg3[2 * NN + n];
    cnt[n] = d0 + d1 + d2;
    dis3[n]          = rsqrtf((float)d0 + 1.f);
    dis3[NN + n]     = rsqrtf((float)d1 + 1.f);
    dis3[2 * NN + n] = rsqrtf((float)d2 + 1.f);
}

// ---------------- exclusive scan of cnt -> per-type segment starts offs3 ----------------
__global__ void scan1_kernel(const int* __restrict__ cnt, int* __restrict__ bsum) {
    __shared__ int s[256];
    int i = blockIdx.x * 256 + threadIdx.x;
    s[threadIdx.x] = (i < NN) ? cnt[i] : 0;
    __syncthreads();
    for (int off = 128; off > 0; off >>= 1) {
        if (threadIdx.x < off) s[threadIdx.x] += s[threadIdx.x + off];
        __syncthreads();
    }
    if (threadIdx.x == 0) bsum[blockIdx.x] = s[0];
}

__global__ void scan2_kernel(int* __restrict__ bsum, int nblk) {
    __shared__ int s[512];
    int tid = threadIdx.x;
    s[tid] = (tid < nblk) ? bsum[tid] : 0;
    __syncthreads();
    for (int off = 1; off < 512; off <<= 1) {
        int t = 0;
        if (tid >= off) t = s[tid - off];
        __syncthreads();
        if (tid >= off) s[tid] += t;
        __syncthreads();
    }
    if (tid < nblk) bsum[tid] = (tid == 0) ? 0 : s[tid - 1];  // exclusive
}

__global__ void scan3_kernel(const int* __restrict__ cnt, const int* __restrict__ bsum,
                             const int* __restrict__ deg3, int* __restrict__ offs3) {
    __shared__ int s[256];
    int i = blockIdx.x * 256 + threadIdx.x;
    int v = (i < NN) ? cnt[i] : 0;
    s[threadIdx.x] = v;
    __syncthreads();
    for (int off = 1; off < 256; off <<= 1) {
        int t = 0;
        if (threadIdx.x >= off) t = s[threadIdx.x - off];
        __syncthreads();
        if (threadIdx.x >= off) s[threadIdx.x] += t;
        __syncthreads();
    }
    if (i < NN) {
        int o = bsum[blockIdx.x] + s[threadIdx.x] - v;  // exclusive
        int d0 = deg3[i], d1 = deg3[NN + i];
        offs3[i]          = o;
        offs3[NN + i]     = o + d0;
        offs3[2 * NN + i] = o + d0 + d1;
    }
}

// ---------------- CSR fill: rec = (src, dis_t[src]), no atomics, MLP=4 ----------------
__global__ void fill_kernel(const int* __restrict__ edges, const int* __restrict__ rank,
                            const float* __restrict__ dis3, const int* __restrict__ offs3,
                            int2* __restrict__ recs) {
    int t = blockIdx.y;
    int e0 = (blockIdx.x * 256 + threadIdx.x) * 4;
    if (e0 >= EE) return;
    const int* base = edges + (size_t)t * 2 * EE;
    int4 sn = *(const int4*)(base + e0);
    int4 dn = *(const int4*)(base + EE + e0);
    int4 rk = *(const int4*)(rank + (size_t)t * EE + e0);
    const int* o3 = offs3 + t * NN;
    const float* ds = dis3 + t * NN;
    recs[o3[dn.x] + rk.x] = make_int2(sn.x, __float_as_int(ds[sn.x]));
    recs[o3[dn.y] + rk.y] = make_int2(sn.y, __float_as_int(ds[sn.y]));
    recs[o3[dn.z] + rk.z] = make_int2(sn.z, __float_as_int(ds[sn.z]));
    recs[o3[dn.w] + rk.w] = make_int2(sn.w, __float_as_int(ds[sn.w]));
}

// ---------------- fused gather(aggregate in x-space) + MFMA transform + bias ----------------
// Block = 256 thr = 4 waves, 16 nodes. Phase 1: wave w gathers nodes w*4..w*4+3 into
// LDS tile Y[16][3*D] (stride LSTRIDE). Phase 2: out[16 nodes] = sum_t Y_t @ W_t + bias.
__global__ __launch_bounds__(256) void fused_kernel(const bf16_t* __restrict__ xq,
                                                    const float* __restrict__ dis3,
                                                    const int* __restrict__ offs3,
                                                    const int* __restrict__ deg3,
                                                    const int2* __restrict__ recs,
                                                    const bf16_t* __restrict__ WT,
                                                    const float* __restrict__ b,
                                                    float* __restrict__ out) {
    __shared__ ushort ylds[16 * LSTRIDE];
    __shared__ float bias[D];
    int tid  = threadIdx.x;
    int lane = tid & 63;
    int wave = tid >> 6;

    if (tid < D) bias[tid] = b[tid] + b[D + tid] + b[2 * D + tid];

    int n0 = blockIdx.x * 16;   // NN % 16 == 0

    // ---- phase 1: aggregation into LDS (lane owns dims 2*lane, 2*lane+1) ----
    for (int v = 0; v < 4; ++v) {
        int r = wave * 4 + v;               // local row 0..15
        int n = n0 + r;
        unsigned su = *(const unsigned*)(xq + (size_t)n * D + lane * 2);
        float xs0 = bf_lo(su), xs1 = bf_hi(su);
#pragma unroll
        for (int t = 0; t < TT; ++t) {
            float dnv = dis3[t * NN + n];
            int s0 = offs3[t * NN + n];
            int c  = deg3[t * NN + n];
            float a0 = dnv * xs0, a1 = dnv * xs1;   // self-loop term
            int j = 0;
            for (; j + 4 <= c; j += 4) {
                int2 r0 = recs[s0 + j];
                int2 r1 = recs[s0 + j + 1];
                int2 r2 = recs[s0 + j + 2];
                int2 r3 = recs[s0 + j + 3];
                unsigned u0 = *(const unsigned*)(xq + (size_t)r0.x * D + lane * 2);
                unsigned u1 = *(const unsigned*)(xq + (size_t)r1.x * D + lane * 2);
                unsigned u2 = *(const unsigned*)(xq + (size_t)r2.x * D + lane * 2);
                unsigned u3 = *(const unsigned*)(xq + (size_t)r3.x * D + lane * 2);
                float w0 = __int_as_float(r0.y), w1 = __int_as_float(r1.y);
                float w2 = __int_as_float(r2.y), w3 = __int_as_float(r3.y);
                a0 += w0 * bf_lo(u0) + w1 * bf_lo(u1) + w2 * bf_lo(u2) + w3 * bf_lo(u3);
                a1 += w0 * bf_hi(u0) + w1 * bf_hi(u1) + w2 * bf_hi(u2) + w3 * bf_hi(u3);
            }
            for (; j < c; ++j) {
                int2 rr = recs[s0 + j];
                unsigned u = *(const unsigned*)(xq + (size_t)rr.x * D + lane * 2);
                float wv = __int_as_float(rr.y);
                a0 += wv * bf_lo(u);
                a1 += wv * bf_hi(u);
            }
            a0 *= dnv; a1 *= dnv;                   // dst-side norm factored out
            unsigned pk = (unsigned)f2bf(a0) | ((unsigned)f2bf(a1) << 16);
            *(unsigned*)(ylds + r * LSTRIDE + t * D + lane * 2) = pk;
        }
    }
    __syncthreads();

    // ---- phase 2: out = sum_t Y_t @ W_t + bias (MFMA 16x16x32, K = 3*128) ----
    int quad = lane >> 4;
    int lid  = lane & 15;

    ABFrag a[12];   // [t*4+s], A[m=lid][k=s*32+quad*8+j]
#pragma unroll
    for (int t = 0; t < TT; ++t)
#pragma unroll
        for (int s = 0; s < 4; ++s)
            a[t * 4 + s].q = *(const uint4*)(ylds + lid * LSTRIDE + t * D + s * 32 + quad * 8);

#pragma unroll
    for (int p = 0; p < 2; ++p) {
        int nb  = wave + p * 4;           // 4 waves x 2 -> 8 col-blocks of 16
        int col = nb * 16 + lid;
        f32x4_t acc = {0.f, 0.f, 0.f, 0.f};
#pragma unroll
        for (int t = 0; t < TT; ++t) {
            const bf16_t* wn = WT + ((size_t)t * D + col) * D;   // B[n=col][k]
#pragma unroll
            for (int s = 0; s < 4; ++s) {
                ABFrag bfr;
                bfr.q = *(const uint4*)(wn + s * 32 + quad * 8);
                acc = __builtin_amdgcn_mfma_f32_16x16x32_bf16(a[t * 4 + s].v, bfr.v, acc, 0, 0, 0);
            }
        }
        float bc = bias[col];
#pragma unroll
        for (int rr = 0; rr < 4; ++rr) {
            int m = quad * 4 + rr;        // C/D: row = quad*4 + reg
            out[(size_t)(n0 + m) * D + col] = acc[rr] + bc;
        }
    }
}

extern "C" void kernel_launch(void* const* d_in, const int* in_sizes, int n_in,
                              void* d_out, int out_size, void* d_ws, size_t ws_size,
                              hipStream_t stream) {
    const float* x     = (const float*)d_in[0];   // [NN, D]
    const int*   edges = (const int*)d_in[1];     // [TT, 2, EE]
    const float* W     = (const float*)d_in[2];   // [TT, D, D]
    const float* b     = (const float*)d_in[3];   // [TT, D]
    float*       out   = (float*)d_out;           // [NN, D]

    // workspace layout (~58.5 MB total)
    char* w = (char*)d_ws;
    bf16_t* xq    = (bf16_t*)w;                                   // NN*D bf16 = 25.6 MB
    float*  dis3  = (float*)(w + (size_t)NN * D * 2);             // 3*NN f32 = 1.2 MB
    int*    deg3  = (int*)((char*)dis3 + (size_t)3 * NN * 4);     // 3*NN
    int*    cnt   = deg3 + 3 * NN;                                // NN
    int*    offs3 = cnt + NN;                                     // 3*NN
    int*    bsum  = offs3 + 3 * NN;                               // 512
    int*    rank  = bsum + 512;                                   // 3*EE = 9.6 MB
    int2*   recs  = (int2*)(rank + (size_t)3 * EE);               // 3*EE int2 = 19.2 MB
    bf16_t* WT    = (bf16_t*)(recs + (size_t)3 * EE);             // 3*D*D bf16 = 96 KB

    const int nblk = (NN + 255) / 256;  // 391

    hipMemsetAsync(deg3, 0, (size_t)3 * NN * sizeof(int), stream);

    // 0) x -> bf16 copy; W -> bf16 transposed
    quant_kernel<<<(NN * D / 4 + 255) / 256, 256, 0, stream>>>(x, xq);
    {
        dim3 g(D, TT);
        wconv_kernel<<<g, D, 0, stream>>>(W, WT);
    }

    // 1) degree + rank
    {
        dim3 g((EE / 4 + 255) / 256, TT);
        deg_rank_kernel<<<g, 256, 0, stream>>>(edges, deg3, rank);
    }
    dis_cnt_kernel<<<nblk, 256, 0, stream>>>(deg3, dis3, cnt);

    // 2) scan -> per-type segment starts
    scan1_kernel<<<nblk, 256, 0, stream>>>(cnt, bsum);
    scan2_kernel<<<1, 512, 0, stream>>>(bsum, nblk);
    scan3_kernel<<<nblk, 256, 0, stream>>>(cnt, bsum, deg3, offs3);

    // 3) fill CSR records (src, dis_src)
    {
        dim3 g((EE / 4 + 255) / 256, TT);
        fill_kernel<<<g, 256, 0, stream>>>(edges, rank, dis3, offs3, recs);
    }

    // 4) fused aggregate (x-space) + MFMA transform + bias -> out
    fused_kernel<<<NN / 16, 256, 0, stream>>>(xq, dis3, offs3, deg3, recs, WT, b, out);
}

// Round 6
// 470.542 us; speedup vs baseline: 10.5469x; 1.0433x over previous
//
#include <hip/hip_runtime.h>

#define NN 100000      // nodes
#define EE 800000      // edges per type
#define TT 3           // edge types
#define D  128         // feature dim
#define LSTRIDE 392    // 3*D + 8 pad (elements)

typedef unsigned short bf16_t;

typedef __bf16 bf16x8_t __attribute__((ext_vector_type(8)));
typedef float  f32x4_t  __attribute__((ext_vector_type(4)));

union ABFrag { bf16x8_t v; ushort u[8]; uint4 q; };

__device__ __forceinline__ bf16_t f2bf(float f) {
    unsigned u = __float_as_uint(f);
    u += 0x7fff + ((u >> 16) & 1);      // round-to-nearest-even
    return (bf16_t)(u >> 16);
}
__device__ __forceinline__ float bf_lo(unsigned p) { return __uint_as_float(p << 16); }
__device__ __forceinline__ float bf_hi(unsigned p) { return __uint_as_float(p & 0xFFFF0000u); }

// ---------------- quantize x -> bf16 copy (25.6 MB gather target) ----------------
__global__ void quant_kernel(const float* __restrict__ x, bf16_t* __restrict__ xq) {
    int i = (blockIdx.x * 256 + threadIdx.x) * 4;
    if (i >= NN * D) return;
    float4 f = *(const float4*)(x + i);
    uint2 p;
    p.x = (unsigned)f2bf(f.x) | ((unsigned)f2bf(f.y) << 16);
    p.y = (unsigned)f2bf(f.z) | ((unsigned)f2bf(f.w) << 16);
    *(uint2*)(xq + i) = p;
}

// ---------------- W transpose + bf16: WT[t][n][k] = bf16(W[t][k][n]) ----------------
__global__ void wconv_kernel(const float* __restrict__ W, bf16_t* __restrict__ WT) {
    int t = blockIdx.y, n = blockIdx.x, k = threadIdx.x;
    WT[((size_t)t * D + n) * D + k] = f2bf(W[((size_t)t * D + k) * D + n]);
}

// ---------------- degree + rank (atomic return = within-segment rank), MLP=4 ----------------
__global__ void deg_rank_kernel(const int* __restrict__ edges, int* __restrict__ deg3,
                                int* __restrict__ rank) {
    int t = blockIdx.y;
    int e0 = (blockIdx.x * 256 + threadIdx.x) * 4;
    if (e0 >= EE) return;                         // EE % 4 == 0
    const int* dstp = edges + (size_t)t * 2 * EE + EE;
    int4 dn = *(const int4*)(dstp + e0);
    int* dg = deg3 + t * NN;
    int4 r;
    r.x = atomicAdd(&dg[dn.x], 1);
    r.y = atomicAdd(&dg[dn.y], 1);
    r.z = atomicAdd(&dg[dn.z], 1);
    r.w = atomicAdd(&dg[dn.w], 1);
    *(int4*)(rank + (size_t)t * EE + e0) = r;
}

// dis3[t][n] = rsqrt(deg+1); cnt[n] = total in-degree over types
__global__ void dis_cnt_kernel(const int* __restrict__ deg3, float* __restrict__ dis3,
                               int* __restrict__ cnt) {
    int n = blockIdx.x * 256 + threadIdx.x;
    if (n >= NN) return;
    int d0 = deg3[n], d1 = deg3[NN + n], d2 = deg3[2 * NN + n];
    cnt[n] = d0 + d1 + d2;
    dis3[n]          = rsqrtf((float)d0 + 1.f);
    dis3[NN + n]     = rsqrtf((float)d1 + 1.f);
    dis3[2 * NN + n] = rsqrtf((float)d2 + 1.f);
}

// ---------------- exclusive scan of cnt -> per-type segment starts offs3 ----------------
__global__ void scan1_kernel(const int* __restrict__ cnt, int* __restrict__ bsum) {
    __shared__ int s[256];
    int i = blockIdx.x * 256 + threadIdx.x;
    s[threadIdx.x] = (i < NN) ? cnt[i] : 0;
    __syncthreads();
    for (int off = 128; off > 0; off >>= 1) {
        if (threadIdx.x < off) s[threadIdx.x] += s[threadIdx.x + off];
        __syncthreads();
    }
    if (threadIdx.x == 0) bsum[blockIdx.x] = s[0];
}

__global__ void scan2_kernel(int* __restrict__ bsum, int nblk) {
    __shared__ int s[512];
    int tid = threadIdx.x;
    s[tid] = (tid < nblk) ? bsum[tid] : 0;
    __syncthreads();
    for (int off = 1; off < 512; off <<= 1) {
        int t = 0;
        if (tid >= off) t = s[tid - off];
        __syncthreads();
        if (tid >= off) s[tid] += t;
        __syncthreads();
    }
    if (tid < nblk) bsum[tid] = (tid == 0) ? 0 : s[tid - 1];  // exclusive
}

__global__ void scan3_kernel(const int* __restrict__ cnt, const int* __restrict__ bsum,
                             const int* __restrict__ deg3, int* __restrict__ offs3) {
    __shared__ int s[256];
    int i = blockIdx.x * 256 + threadIdx.x;
    int v = (i < NN) ? cnt[i] : 0;
    s[threadIdx.x] = v;
    __syncthreads();
    for (int off = 1; off < 256; off <<= 1) {
        int t = 0;
        if (threadIdx.x >= off) t = s[threadIdx.x - off];
        __syncthreads();
        if (threadIdx.x >= off) s[threadIdx.x] += t;
        __syncthreads();
    }
    if (i < NN) {
        int o = bsum[blockIdx.x] + s[threadIdx.x] - v;  // exclusive
        int d0 = deg3[i], d1 = deg3[NN + i];
        offs3[i]          = o;
        offs3[NN + i]     = o + d0;
        offs3[2 * NN + i] = o + d0 + d1;
    }
}

// ---------------- CSR fill: rec = (src, dis_t[src]), no atomics, MLP=4 ----------------
__global__ void fill_kernel(const int* __restrict__ edges, const int* __restrict__ rank,
                            const float* __restrict__ dis3, const int* __restrict__ offs3,
                            int2* __restrict__ recs) {
    int t = blockIdx.y;
    int e0 = (blockIdx.x * 256 + threadIdx.x) * 4;
    if (e0 >= EE) return;
    const int* base = edges + (size_t)t * 2 * EE;
    int4 sn = *(const int4*)(base + e0);
    int4 dn = *(const int4*)(base + EE + e0);
    int4 rk = *(const int4*)(rank + (size_t)t * EE + e0);
    const int* o3 = offs3 + t * NN;
    const float* ds = dis3 + t * NN;
    recs[o3[dn.x] + rk.x] = make_int2(sn.x, __float_as_int(ds[sn.x]));
    recs[o3[dn.y] + rk.y] = make_int2(sn.y, __float_as_int(ds[sn.y]));
    recs[o3[dn.z] + rk.z] = make_int2(sn.z, __float_as_int(ds[sn.z]));
    recs[o3[dn.w] + rk.w] = make_int2(sn.w, __float_as_int(ds[sn.w]));
}

// ---------------- fused: wave-per-node gather (x-space) + MFMA transform + bias ------------
// Block = 1024 thr = 16 waves = 16 nodes. Phase 1: wave w aggregates node n0+w into LDS row w
// using a 64-record register window + readlane scalarization (8 loads in flight).
// Phase 2: waves 0..7 compute out[16 x 128] = sum_t Y_t @ W_t + bias via MFMA 16x16x32.
__global__ __launch_bounds__(1024, 4) void fused_kernel(const bf16_t* __restrict__ xq,
                                                        const float* __restrict__ dis3,
                                                        const int* __restrict__ offs3,
                                                        const int* __restrict__ deg3,
                                                        const int2* __restrict__ recs,
                                                        const bf16_t* __restrict__ WT,
                                                        const float* __restrict__ b,
                                                        float* __restrict__ out) {
    __shared__ ushort ylds[16 * LSTRIDE];
    int tid  = threadIdx.x;
    int lane = tid & 63;
    int wave = tid >> 6;            // 0..15 = local node index
    int n0 = blockIdx.x * 16;       // NN % 16 == 0
    int n  = n0 + wave;

    unsigned su = *(const unsigned*)(xq + (size_t)n * D + lane * 2);
    float xs0 = bf_lo(su), xs1 = bf_hi(su);

#pragma unroll
    for (int t = 0; t < TT; ++t) {
        float dnv = dis3[t * NN + n];
        int s0 = offs3[t * NN + n];
        int c  = deg3[t * NN + n];
        float a0 = dnv * xs0, a1 = dnv * xs1;    // self-loop term
        for (int base = 0; base < c; base += 64) {
            int m = c - base; if (m > 64) m = 64;
            int2 rl = recs[s0 + base + (lane < m ? lane : 0)];   // record window in registers
            int j = 0;
            for (; j + 8 <= m; j += 8) {
                int   sx[8]; float wx[8]; unsigned ux[8];
#pragma unroll
                for (int k = 0; k < 8; ++k) {
                    sx[k] = __builtin_amdgcn_readlane(rl.x, j + k);            // SGPR
                    wx[k] = __uint_as_float(__builtin_amdgcn_readlane(rl.y, j + k));
                }
#pragma unroll
                for (int k = 0; k < 8; ++k)
                    ux[k] = *(const unsigned*)(xq + (size_t)sx[k] * D + lane * 2);
#pragma unroll
                for (int k = 0; k < 8; ++k) {
                    a0 += wx[k] * bf_lo(ux[k]);
                    a1 += wx[k] * bf_hi(ux[k]);
                }
            }
            for (; j < m; ++j) {
                int   sj = __builtin_amdgcn_readlane(rl.x, j);
                float wj = __uint_as_float(__builtin_amdgcn_readlane(rl.y, j));
                unsigned u = *(const unsigned*)(xq + (size_t)sj * D + lane * 2);
                a0 += wj * bf_lo(u);
                a1 += wj * bf_hi(u);
            }
        }
        a0 *= dnv; a1 *= dnv;                    // dst-side norm
        *(unsigned*)(ylds + wave * LSTRIDE + t * D + lane * 2) =
            (unsigned)f2bf(a0) | ((unsigned)f2bf(a1) << 16);
    }
    __syncthreads();

    // ---- phase 2: 8 active waves, wave w -> column block w ----
    if (wave < 8) {
        int quad = lane >> 4;
        int lid  = lane & 15;
        int col  = wave * 16 + lid;

        ABFrag a[12];   // A[m=lid][k = t*128 + s*32 + quad*8 + j]
#pragma unroll
        for (int t = 0; t < TT; ++t)
#pragma unroll
            for (int s = 0; s < 4; ++s)
                a[t * 4 + s].q = *(const uint4*)(ylds + lid * LSTRIDE + t * D + s * 32 + quad * 8);

        f32x4_t acc = {0.f, 0.f, 0.f, 0.f};
#pragma unroll
        for (int t = 0; t < TT; ++t) {
            const bf16_t* wn = WT + ((size_t)t * D + col) * D;   // B[n=col][k]
#pragma unroll
            for (int s = 0; s < 4; ++s) {
                ABFrag bfr;
                bfr.q = *(const uint4*)(wn + s * 32 + quad * 8);
                acc = __builtin_amdgcn_mfma_f32_16x16x32_bf16(a[t * 4 + s].v, bfr.v, acc, 0, 0, 0);
            }
        }
        float bc = b[col] + b[D + col] + b[2 * D + col];
#pragma unroll
        for (int r = 0; r < 4; ++r)
            out[(size_t)(n0 + quad * 4 + r) * D + col] = acc[r] + bc;  // C/D: row=quad*4+reg
    }
}

extern "C" void kernel_launch(void* const* d_in, const int* in_sizes, int n_in,
                              void* d_out, int out_size, void* d_ws, size_t ws_size,
                              hipStream_t stream) {
    const float* x     = (const float*)d_in[0];   // [NN, D]
    const int*   edges = (const int*)d_in[1];     // [TT, 2, EE]
    const float* W     = (const float*)d_in[2];   // [TT, D, D]
    const float* b     = (const float*)d_in[3];   // [TT, D]
    float*       out   = (float*)d_out;           // [NN, D]

    // workspace layout (~59 MB total)
    char* w = (char*)d_ws;
    bf16_t* xq    = (bf16_t*)w;                                   // NN*D bf16 = 25.6 MB
    float*  dis3  = (float*)(w + (size_t)NN * D * 2);             // 3*NN f32
    int*    deg3  = (int*)((char*)dis3 + (size_t)3 * NN * 4);     // 3*NN
    int*    cnt   = deg3 + 3 * NN;                                // NN
    int*    offs3 = cnt + NN;                                     // 3*NN
    int*    bsum  = offs3 + 3 * NN;                               // 512
    int*    rank  = bsum + 512;                                   // 3*EE = 9.6 MB
    int2*   recs  = (int2*)(rank + (size_t)3 * EE);               // 3*EE int2 = 19.2 MB
    bf16_t* WT    = (bf16_t*)(recs + (size_t)3 * EE);             // 3*D*D bf16 = 96 KB

    const int nblk = (NN + 255) / 256;  // 391

    hipMemsetAsync(deg3, 0, (size_t)3 * NN * sizeof(int), stream);

    // 0) x -> bf16 copy; W -> bf16 transposed
    quant_kernel<<<(NN * D / 4 + 255) / 256, 256, 0, stream>>>(x, xq);
    {
        dim3 g(D, TT);
        wconv_kernel<<<g, D, 0, stream>>>(W, WT);
    }

    // 1) degree + rank
    {
        dim3 g((EE / 4 + 255) / 256, TT);
        deg_rank_kernel<<<g, 256, 0, stream>>>(edges, deg3, rank);
    }
    dis_cnt_kernel<<<nblk, 256, 0, stream>>>(deg3, dis3, cnt);

    // 2) scan -> per-type segment starts
    scan1_kernel<<<nblk, 256, 0, stream>>>(cnt, bsum);
    scan2_kernel<<<1, 512, 0, stream>>>(bsum, nblk);
    scan3_kernel<<<nblk, 256, 0, stream>>>(cnt, bsum, deg3, offs3);

    // 3) fill CSR records (src, dis_src)
    {
        dim3 g((EE / 4 + 255) / 256, TT);
        fill_kernel<<<g, 256, 0, stream>>>(edges, rank, dis3, offs3, recs);
    }

    // 4) fused wave-per-node aggregate + MFMA transform + bias -> out
    fused_kernel<<<NN / 16, 1024, 0, stream>>>(xq, dis3, offs3, deg3, recs, WT, b, out);
}